// Round 15
// baseline (187.038 us; speedup 1.0000x reference)
//
#include <hip/hip_runtime.h>

// MomentumSSM B=2, L=4096, D=512, N=16, R=32, P=64 — chunk-parallel scan, NCH=256.
// R29: R28 (best, 156.1us) + scan1 lane-pair rebuilt for VGPR<=64 (8 waves/SIMD).
//   k_proj (MFMA bf16x3) -> k_scan1(lane-pair, <=64 VGPR) -> k_fix(par) -> k_scan2
// - RESOLVING THE R17 CONFOUND: R17's lane-pair kept xs[16]+A2h[8]+full w4 ->
//   ~90-100 VGPR = SAME 65-128 occupancy band as baseline (m69: waves halve at
//   64/128/256) -> occupancy never changed -> neutrality was guaranteed, TLP
//   hypothesis untested. This version targets <=64 VGPR: 8 states (24), K-split
//   w4 (16), xs STREAMED (2 live), A2h dropped (pw needs a0 only), ar chain
//   halved (hf=1 seeds r^8). GATE: VGPR<=64 in counters, else clean null.
// - scan2/k_fix/k_proj byte-identical to R28; state layouts bit-identical.
// Budget @156: scans ~96, k_fix ~9, proj ~9, gaps ~5, harness fill ~44 (fixed).
// TOOLCHAIN LANDMINES (measured):
//   * __launch_bounds__(N, waves) 2nd arg caps VGPR at 64 -> spills (R15/R16).
//   * 1024-thread blocks cap VGPR at 64 -> keep per-thread state tiny (R25).
//   * scans at VGPR=128 sit on an occupancy cliff; bands are 64/128/256 (R27).
//   * runtime-indexed private arrays -> promote-alloca-to-LDS + conflicts (R16).
//   * k_fix lanes must map to contiguous series dim (dn), never chunk/span (R23).
// Disproven: coop launch, manual grid barrier, dt recompute in scan2, scan LDS
// elimination (R18), serial proj fusion (R20), NCH=512 (R22/R25), span-major
// k_fix lanes (R23), independent-exp2 ar at VGPR=128 (R27 cliff).
//
// v_t = beta*v + alpha*inp ; h_t = a_t*h + v ; a_t = exp(dt*A_n)
// chunk map: h_end = Pa*H0 + cv*V0 + hhat ; v_end = beta^LCH*V0 + vhat
// map compose C=B∘A: P=BP*AP; q=BP*Aq+Bq*Aw; h=BP*Ah+Bq*Av+Bh; v=Bw*Av+Bv; w=Bw*Aw

#define D_IN 512
#define D_ST 16
#define DTR  32
#define BSZ  2
#define LSEQ 4096
#define PDIM 64
#define NCH  256
#define LCH  (LSEQ / NCH)  // 16
#define LOG2E 1.44269504f
#define LN2   0.69314718f

typedef __attribute__((ext_vector_type(8))) short short8;
typedef __attribute__((ext_vector_type(4))) float f32x4;
typedef _Float16 f16;
typedef __attribute__((ext_vector_type(8))) _Float16 f16x8;

__device__ inline float fast_exp2(float x) { return __builtin_amdgcn_exp2f(x); }
__device__ inline float fast_log2(float x) { return __builtin_amdgcn_logf(x); }

__device__ inline unsigned short bf16_rne(float f) {
  unsigned b = __float_as_uint(f);
  return (unsigned short)((b + 0x7fffu + ((b >> 16) & 1u)) >> 16);
}

__device__ inline void cvt8(const float4 u, const float4 v, short8& hi, short8& lo) {
  float f[8] = {u.x, u.y, u.z, u.w, v.x, v.y, v.z, v.w};
#pragma unroll
  for (int i = 0; i < 8; ++i) {
    unsigned short h = bf16_rne(f[i]);
    hi[i] = (short)h;
    float r = f[i] - __uint_as_float((unsigned)h << 16);
    lo[i] = (short)bf16_rne(r);
  }
}

__device__ inline void st8h(f16* p, const float* s) {
  f16 t[8];
#pragma unroll
  for (int i = 0; i < 8; ++i) t[i] = (f16)s[i];
  *(f16x8*)p = *(f16x8*)&t[0];
}
__device__ inline void ld16h(const f16* p, float* d) {
  f16x8 a = *(const f16x8*)p;
  f16x8 b = *(const f16x8*)(p + 8);
#pragma unroll
  for (int i = 0; i < 8; ++i) { d[i] = (float)a[i]; d[8 + i] = (float)b[i]; }
}

// pw check: A2[n] = -exp(A_log[d][n])*LOG2E is an arithmetic progression
#define PWCHK(val, n)                                                        \
  pw = pw && (fabsf((val) - (float)((n) + 1) * a0) <=                        \
              2e-5f * fabsf((float)((n) + 1) * a0));

__device__ inline bool detectA2(const float* __restrict__ A_log, int d, float& a0) {
  const float4* ap = (const float4*)(A_log + (size_t)d * D_ST);
  float4 r0 = ap[0], r1 = ap[1], r2 = ap[2], r3 = ap[3];
  float4 e0 = make_float4(-__expf(r0.x) * LOG2E, -__expf(r0.y) * LOG2E,
                          -__expf(r0.z) * LOG2E, -__expf(r0.w) * LOG2E);
  float4 e1 = make_float4(-__expf(r1.x) * LOG2E, -__expf(r1.y) * LOG2E,
                          -__expf(r1.z) * LOG2E, -__expf(r1.w) * LOG2E);
  float4 e2 = make_float4(-__expf(r2.x) * LOG2E, -__expf(r2.y) * LOG2E,
                          -__expf(r2.z) * LOG2E, -__expf(r2.w) * LOG2E);
  float4 e3 = make_float4(-__expf(r3.x) * LOG2E, -__expf(r3.y) * LOG2E,
                          -__expf(r3.z) * LOG2E, -__expf(r3.w) * LOG2E);
  a0 = e0.x;
  bool pw = true;
  PWCHK(e0.y, 1) PWCHK(e0.z, 2) PWCHK(e0.w, 3)
  PWCHK(e1.x, 4) PWCHK(e1.y, 5) PWCHK(e1.z, 6) PWCHK(e1.w, 7)
  PWCHK(e2.x, 8) PWCHK(e2.y, 9) PWCHK(e2.z, 10) PWCHK(e2.w, 11)
  PWCHK(e3.x, 12) PWCHK(e3.y, 13) PWCHK(e3.z, 14) PWCHK(e3.w, 15)
  return pw;
}

// ---------------- proj = x @ W^T via MFMA bf16x3, 4-wave K-split -------------
#define MM3(ACC, AH, AL, BH, BL)                                        \
  ACC = __builtin_amdgcn_mfma_f32_16x16x32_bf16(AL, BH, ACC, 0, 0, 0);  \
  ACC = __builtin_amdgcn_mfma_f32_16x16x32_bf16(AH, BL, ACC, 0, 0, 0);  \
  ACC = __builtin_amdgcn_mfma_f32_16x16x32_bf16(AH, BH, ACC, 0, 0, 0);

#define LOADBF(P, S)                                          \
  {                                                           \
    const int kb = (S) * 32;                                  \
    float4 a0 = *(const float4*)(wr + kb);                    \
    float4 b0 = *(const float4*)(wr + kb + 4);                \
    float4 a1 = *(const float4*)(wr + 8192 + kb);             \
    float4 b1 = *(const float4*)(wr + 8192 + kb + 4);         \
    float4 a2 = *(const float4*)(wr + 16384 + kb);            \
    float4 b2 = *(const float4*)(wr + 16384 + kb + 4);        \
    float4 a3 = *(const float4*)(wr + 24576 + kb);            \
    float4 b3 = *(const float4*)(wr + 24576 + kb + 4);        \
    cvt8(a0, b0, P##h0, P##l0);                               \
    cvt8(a1, b1, P##h1, P##l1);                               \
    cvt8(a2, b2, P##h2, P##l2);                               \
    cvt8(a3, b3, P##h3, P##l3);                               \
  }

#define LOADA(Aa, Ab, S)                              \
  {                                                   \
    const int ka = (S) * 32;                          \
    Aa = *(const float4*)(xr + ka);                   \
    Ab = *(const float4*)(xr + ka + 4);               \
  }

#define COMPSTEP(Aa, Ab, P)                           \
  {                                                   \
    short8 ahi, alo;                                  \
    cvt8(Aa, Ab, ahi, alo);                           \
    MM3(acc0, ahi, alo, P##h0, P##l0);                \
    MM3(acc1, ahi, alo, P##h1, P##l1);                \
    MM3(acc2, ahi, alo, P##h2, P##l2);                \
    MM3(acc3, ahi, alo, P##h3, P##l3);                \
  }

__global__ __launch_bounds__(256) void k_proj(const float* __restrict__ x,
                                              const float* __restrict__ W,
                                              float* __restrict__ proj) {
  __shared__ float Pacc[4][16][64];  // 16 KB: per-wave partial C tiles
  const int row0 = blockIdx.x * 16;
  const int l = threadIdx.x & 63;
  const int wq = threadIdx.x >> 6;             // K-quarter owner
  const int m = l & 15;
  const int ko = (l >> 4) * 8 + wq * 128;      // this wave's K window
  const float* xr = x + (size_t)(row0 + m) * D_IN + ko;
  const float* wr = W + (size_t)m * D_IN + ko;

  f32x4 acc0 = {0.f, 0.f, 0.f, 0.f}, acc1 = acc0, acc2 = acc0, acc3 = acc0;
  float4 A0a, A0b, A1a, A1b, A2a, A2b, A3a, A3b;
  short8 Xh0, Xh1, Xh2, Xh3, Xl0, Xl1, Xl2, Xl3;
  short8 Yh0, Yh1, Yh2, Yh3, Yl0, Yl1, Yl2, Yl3;
  LOADA(A0a, A0b, 0); LOADA(A1a, A1b, 1); LOADA(A2a, A2b, 2); LOADA(A3a, A3b, 3);
  LOADBF(X, 0); LOADBF(Y, 1);

  COMPSTEP(A0a, A0b, X); LOADBF(X, 2);
  COMPSTEP(A1a, A1b, Y); LOADBF(Y, 3);
  COMPSTEP(A2a, A2b, X);
  COMPSTEP(A3a, A3b, Y);

  const int r0 = (l >> 4) * 4;
#pragma unroll
  for (int r = 0; r < 4; ++r) {
    Pacc[wq][r0 + r][m] = acc0[r];
    Pacc[wq][r0 + r][16 + m] = acc1[r];
    Pacc[wq][r0 + r][32 + m] = acc2[r];
    Pacc[wq][r0 + r][48 + m] = acc3[r];
  }
  __syncthreads();

  const int orow = threadIdx.x >> 4;           // 0..15
  const int ocol = (threadIdx.x & 15) * 4;     // 0..60
  float4 s0 = *(const float4*)&Pacc[0][orow][ocol];
  float4 s1 = *(const float4*)&Pacc[1][orow][ocol];
  float4 s2 = *(const float4*)&Pacc[2][orow][ocol];
  float4 s3 = *(const float4*)&Pacc[3][orow][ocol];
  float4 o = make_float4((s0.x + s1.x) + (s2.x + s3.x), (s0.y + s1.y) + (s2.y + s3.y),
                         (s0.z + s1.z) + (s2.z + s3.z), (s0.w + s1.w) + (s2.w + s3.w));
  *(float4*)(proj + (size_t)(row0 + orow) * PDIM + ocol) = o;
}

// ---------------- pass 1: lane-pair, <=64 VGPR target, streamed x ------------
// hf = tid&1 owns states [8hf, 8hf+8); d = by*128 + (tid>>1).
// dt dot K-split: lane hf sums proj[k], k in [16hf,16hf+16); combine via shfl_xor.
#define S1P_LOOP                                                             \
  _Pragma("unroll")                                                          \
  for (int j = 0; j < LCH; ++j) {                                            \
    const float xv = xc;                                                     \
    if (j < LCH - 1) xc = xp[(size_t)(j + 1) * D_IN];                        \
    const float* pj = pb + j * PDIM + 16 * hf;                               \
    float c0 = 0.f, c1 = 0.f, c2 = 0.f, c3 = 0.f;                            \
    _Pragma("unroll")                                                        \
    for (int k = 0; k < 4; ++k) {                                            \
      float4 p = ((const float4*)pj)[k];                                     \
      c0 = fmaf(p.x, w4[k].x, c0);                                           \
      c1 = fmaf(p.y, w4[k].y, c1);                                           \
      c2 = fmaf(p.z, w4[k].z, c2);                                           \
      c3 = fmaf(p.w, w4[k].w, c3);                                           \
    }                                                                        \
    const float part = (c0 + c1) + (c2 + c3);                                \
    const float acc = part + __shfl_xor(part, 1, 64) + bb;                   \
    const float ee = fast_exp2(acc * LOG2E);                                 \
    const float dtc = (acc > 20.f) ? acc : LN2 * fast_log2(1.f + ee);        \
    if (hf == 0) dp[(size_t)j * D_IN] = (f16)dtc;                            \
    sd += dtc;                                                               \
    bpow *= beta;                                                            \
    const float u = alpha * dtc * xv;                                        \
    float4 B0 = *(const float4*)(pb + j * PDIM + DTR + 8 * hf);              \
    float4 B1 = *(const float4*)(pb + j * PDIM + DTR + 8 * hf + 4);          \
    const float Bf[8] = {B0.x, B0.y, B0.z, B0.w, B1.x, B1.y, B1.z, B1.w};    \
    AR_INIT;                                                                 \
    _Pragma("unroll")                                                        \
    for (int k = 0; k < 8; ++k) {                                            \
      AR_STEP;                                                               \
      v8[k] = fmaf(beta, v8[k], u * Bf[k]);                                  \
      h8[k] = fmaf(ar, h8[k], v8[k]);                                        \
      cv8[k] = fmaf(ar, cv8[k], bpow);                                       \
    }                                                                        \
  }

__global__ __launch_bounds__(256) void k_scan1(const float* __restrict__ x,
                                               const float* __restrict__ proj,
                                               const float* __restrict__ A_log,
                                               const float* __restrict__ W_dt,
                                               const float* __restrict__ b_dt,
                                               const float* __restrict__ alpha_p,
                                               const float* __restrict__ beta_p,
                                               f16* __restrict__ hh,
                                               f16* __restrict__ vh,
                                               f16* __restrict__ cvv,
                                               float* __restrict__ sdt,
                                               f16* __restrict__ dth) {
  const int c = blockIdx.x, b = blockIdx.z;
  const int hf = threadIdx.x & 1;
  const int d = blockIdx.y * 128 + (threadIdx.x >> 1);
  const int t0 = c * LCH;
  const float* pb = proj + ((size_t)b * LSEQ + t0) * PDIM;  // uniform -> SGPR

  float a0;
  const bool pw = detectA2(A_log, d, a0);  // transient-heavy, before state live

  // K-half of W_dt for this lane (16 regs)
  float4 w4[4];
  {
    const float4* wp = (const float4*)(W_dt + (size_t)d * DTR + 16 * hf);
#pragma unroll
    for (int i = 0; i < 4; ++i) w4[i] = wp[i];
  }
  const float bb = b_dt[d];
  const float alpha = alpha_p[0];
  const float beta = 1.f / (1.f + __expf(-beta_p[0]));

  const float* xp = x + ((size_t)b * LSEQ + t0) * D_IN + d;
  f16* dp = dth + ((size_t)b * LSEQ + t0) * D_IN + d;
  float xc = xp[0];  // streamed x (2 live values)

  float h8[8] = {}, v8[8] = {}, cv8[8] = {};
  float bpow = 1.f, sd = 0.f;

  if (pw) {
#define AR_INIT                                                   \
    const float r = fast_exp2(dtc * a0);                          \
    float ar;                                                     \
    {                                                             \
      const float r2 = r * r;                                     \
      const float r4 = r2 * r2;                                   \
      ar = hf ? r4 * r4 : 1.f;                                    \
    }
#define AR_STEP ar *= r
    S1P_LOOP
#undef AR_INIT
#undef AR_STEP
  } else {
    volatile const float* av = A_log + (size_t)d * D_ST + 8 * hf;
#define AR_INIT float ar
#define AR_STEP ar = fast_exp2(dtc * (-__expf(av[k]) * LOG2E))
    S1P_LOOP
#undef AR_INIT
#undef AR_STEP
  }

  const size_t base = ((size_t)(b * NCH + c) * D_IN + d) * D_ST + hf * 8;
  st8h(hh + base, h8);
  st8h(vh + base, v8);
  st8h(cvv + base, cv8);
  if (hf == 0) sdt[(size_t)(b * NCH + c) * D_IN + d] = sd;
}

// ---------------- fixup: parallel affine scan, coalesced ---------------------
__global__ __launch_bounds__(1024) void k_fix(f16* __restrict__ hh,
                                              f16* __restrict__ vh,
                                              const f16* __restrict__ cvv,
                                              const float* __restrict__ sdt,
                                              const float* __restrict__ A_log,
                                              const float* __restrict__ beta_p) {
  __shared__ float M[16][5][64];  // 20 KB span maps
  const int lane = threadIdx.x & 63;
  const int w = threadIdx.x >> 6;         // span 0..15
  const int g = blockIdx.x * 64 + lane;   // series id
  const int b = g >> 13;
  const int dn = g & 8191;
  const float beta = 1.f / (1.f + __expf(-beta_p[0]));
  const float A2 = -__expf(A_log[dn]) * LOG2E;
  float bL = beta;
#pragma unroll
  for (int i = 0; i < 4; ++i) bL *= bL;  // beta^16 = beta^LCH

  const size_t cs = (size_t)D_IN * D_ST;
  const size_t base = (size_t)b * NCH * cs + dn;
  const size_t sbase = (size_t)b * NCH * D_IN + (dn >> 4);
  const int c0 = w * 16;

  float hc[16], vc[16], cvc[16], Pa[16];
#pragma unroll
  for (int i = 0; i < 16; ++i) {
    const int c = c0 + i;
    hc[i] = (float)hh[base + (size_t)c * cs];
    vc[i] = (float)vh[base + (size_t)c * cs];
    cvc[i] = (float)cvv[base + (size_t)c * cs];
    Pa[i] = fast_exp2(sdt[sbase + (size_t)c * D_IN] * A2);
  }
  float SP = 1.f, Sq = 0.f, Sh = 0.f, Sv = 0.f, Sw = 1.f;
#pragma unroll
  for (int i = 0; i < 16; ++i) {
    Sq = fmaf(Pa[i], Sq, cvc[i] * Sw);
    Sh = fmaf(Pa[i], Sh, fmaf(cvc[i], Sv, hc[i]));
    SP = Pa[i] * SP;
    Sv = fmaf(bL, Sv, vc[i]);
    Sw = bL * Sw;
  }
  M[w][0][lane] = SP; M[w][1][lane] = Sq; M[w][2][lane] = Sh;
  M[w][3][lane] = Sv; M[w][4][lane] = Sw;
  __syncthreads();

  float H = 0.f, V = 0.f;
  for (int s = 0; s < w; ++s) {
    const float P = M[s][0][lane], q = M[s][1][lane], h = M[s][2][lane];
    const float vv = M[s][3][lane], ww = M[s][4][lane];
    const float Hn = fmaf(P, H, fmaf(q, V, h));
    V = fmaf(ww, V, vv);
    H = Hn;
  }

#pragma unroll
  for (int i = 0; i < 16; ++i) {
    const int c = c0 + i;
    hh[base + (size_t)c * cs] = (f16)H;
    vh[base + (size_t)c * cs] = (f16)V;
    const float Hn = fmaf(Pa[i], H, fmaf(cvc[i], V, hc[i]));
    V = fmaf(bL, V, vc[i]);
    H = Hn;
  }
}

// ---------------- pass 2: LDS-free, read dt(fp16)+x, emit y ------------------
#define S2_LOOP                                                              \
  _Pragma("unroll")                                                          \
  for (int j = 0; j < LCH; ++j) {                                            \
    const float4* pj = (const float4*)(pb + j * PDIM);                       \
    float4 bq[8];                                                            \
    _Pragma("unroll")                                                        \
    for (int k = 0; k < 8; ++k) bq[k] = pj[8 + k];                           \
    const float* Bf = (const float*)bq;                                      \
    const float dtc = dtv[j], xv = xs[j];                                    \
    const float u = alpha * dtc * xv;                                        \
    float y0 = 0.f, y1 = 0.f, y2 = 0.f, y3 = 0.f;                            \
    AR_INIT;                                                                 \
    _Pragma("unroll")                                                        \
    for (int n = 0; n < 16; ++n) {                                           \
      AR_STEP;                                                               \
      v[n] = fmaf(beta, v[n], u * Bf[n]);                                    \
      h[n] = fmaf(ar, h[n], v[n]);                                           \
      float hc = h[n] * Bf[16 + n];                                          \
      if ((n & 3) == 0) y0 += hc;                                            \
      else if ((n & 3) == 1) y1 += hc;                                       \
      else if ((n & 3) == 2) y2 += hc;                                       \
      else y3 += hc;                                                         \
    }                                                                        \
    op[(size_t)j * D_IN] = (y0 + y1) + (y2 + y3) + Dv * xv;                  \
  }

__global__ __launch_bounds__(256) void k_scan2(const float* __restrict__ x,
                                               const f16* __restrict__ dth,
                                               const float* __restrict__ proj,
                                               const float* __restrict__ A_log,
                                               const float* __restrict__ D_param,
                                               const float* __restrict__ alpha_p,
                                               const float* __restrict__ beta_p,
                                               const f16* __restrict__ hh,
                                               const f16* __restrict__ vh,
                                               float* __restrict__ out) {
  const int c = blockIdx.x, b = blockIdx.z;
  const int d = blockIdx.y * 256 + threadIdx.x;
  const int t0 = c * LCH;
  const float* pb = proj + ((size_t)b * LSEQ + t0) * PDIM;  // uniform addr

  float xs[LCH], dtv[LCH];
  {
    const float* xp = x + ((size_t)b * LSEQ + t0) * D_IN + d;
    const f16* dp = dth + ((size_t)b * LSEQ + t0) * D_IN + d;
#pragma unroll
    for (int j = 0; j < LCH; ++j) xs[j] = xp[(size_t)j * D_IN];
#pragma unroll
    for (int j = 0; j < LCH; ++j) dtv[j] = (float)dp[(size_t)j * D_IN];
  }
  const float alpha = alpha_p[0];
  const float beta = 1.f / (1.f + __expf(-beta_p[0]));
  const float Dv = D_param[d];
  float a0;
  const bool pw = detectA2(A_log, d, a0);
  const size_t ibase = ((size_t)(b * NCH + c) * D_IN + d) * D_ST;
  float h[16], v[16];
  ld16h(hh + ibase, h);
  ld16h(vh + ibase, v);

  float* op = out + ((size_t)b * LSEQ + t0) * D_IN + d;
  if (pw) {
#define AR_INIT const float r = fast_exp2(dtc * a0); float ar = 1.f
#define AR_STEP ar *= r
    S2_LOOP
#undef AR_INIT
#undef AR_STEP
  } else {
    volatile const float* av = A_log + (size_t)d * D_ST;
#define AR_INIT float ar
#define AR_STEP ar = fast_exp2(dtc * (-__expf(av[n]) * LOG2E))
    S2_LOOP
#undef AR_INIT
#undef AR_STEP
  }
}

extern "C" void kernel_launch(void* const* d_in, const int* in_sizes, int n_in,
                              void* d_out, int out_size, void* d_ws, size_t ws_size,
                              hipStream_t stream) {
  const float* x = (const float*)d_in[0];
  const float* A_log = (const float*)d_in[1];
  const float* D_param = (const float*)d_in[2];
  const float* W_xproj = (const float*)d_in[3];
  const float* W_dt = (const float*)d_in[4];
  const float* b_dt = (const float*)d_in[5];
  const float* alpha = (const float*)d_in[6];
  const float* beta_logit = (const float*)d_in[7];
  float* out = (float*)d_out;

  const size_t NST = (size_t)BSZ * NCH * D_IN * D_ST;  // 4194304
  float* ws = (float*)d_ws;
  float* proj = ws;                                  // 524288 floats
  float* sdt = proj + (size_t)BSZ * LSEQ * PDIM;     // 262144 floats
  f16* hh = (f16*)(sdt + (size_t)BSZ * NCH * D_IN);  // 4194304 halves
  f16* vh = hh + NST;
  f16* cvv = vh + NST;
  f16* dth = cvv + NST;                              // B*L*D halves; total ~35 MB

  k_proj<<<dim3(BSZ * LSEQ / 16), dim3(256), 0, stream>>>(x, W_xproj, proj);
  k_scan1<<<dim3(NCH, D_IN / 128, BSZ), dim3(256), 0, stream>>>(
      x, proj, A_log, W_dt, b_dt, alpha, beta_logit, hh, vh, cvv, sdt, dth);
  k_fix<<<dim3(BSZ * D_IN * D_ST / 64), dim3(1024), 0, stream>>>(hh, vh, cvv, sdt,
                                                                 A_log, beta_logit);
  k_scan2<<<dim3(NCH, D_IN / 256, BSZ), dim3(256), 0, stream>>>(
      x, dth, proj, A_log, D_param, alpha, beta_logit, hh, vh, out);
}

// Round 16
// 155.030 us; speedup vs baseline: 1.2065x; 1.2065x over previous
//
#include <hip/hip_runtime.h>

// MomentumSSM B=2, L=4096, D=512, N=16, R=32, P=64 — chunk-parallel scan, NCH=256.
// R30 = FINAL: R24/R26/R28 revert (session best, 156.1us; start was 172.5, -9.5%).
//   k_proj (MFMA bf16x3, inline W split) -> k_scan1 -> k_fix(par, coalesced) -> k_scan2
// R29 post-mortem: lane-pair "VGPR<=64" rebuild landed at VGPR=160 (allocator
//   inflated addressing + transients past the 128 cliff) -> occ 10.4%, 69.7us.
//   THIRD consecutive regalloc failure on scan1 restructures (R25, R27, R29):
//   the TLP hypothesis is untestable at source level on this toolchain — every
//   occupancy-buying restructure costs more registers than it saves, and
//   __launch_bounds__ arg 2 (the forcing knob) itself caps VGPR at 64 + spills.
// Session wins: k_proj 4-wave K-split occupancy fix + k_fix group-16 (R19, -8us),
//   wprep folded into k_proj (R21, -1.5us), coalesced parallel k_fix (R24, -10us).
// Final budget @156: scans ~96 (latency plateau: no pipe >22% busy, MFMA 0, LDS 0,
//   HBM 11%; 3 operand paths, 2 wave counts, 2 chunk lengths, 3 inner-loop
//   restructures all neutral-or-worse), k_fix ~9, proj ~9, gaps ~5,
//   harness 256MiB in-stream poison-fill ~44 (fixed overhead).
// TOOLCHAIN LANDMINES (measured):
//   * __launch_bounds__(N, waves) 2nd arg caps VGPR at 64 -> spills (R15/R16).
//   * 1024-thread blocks cap VGPR at 64 -> keep per-thread state tiny (R25).
//   * scans sit at exactly VGPR=128; occupancy bands at 64/128/256 (R27/R29).
//   * runtime-indexed private arrays -> promote-alloca-to-LDS + conflicts (R16).
//   * materializing reg-resident intermediates through HBM between kernels (R15).
//   * k_fix lanes must map to contiguous series dim (dn), never chunk/span (R23).
// Disproven: coop launch, manual grid barrier (~80us/sync), dt recompute in scan2,
// scan1 lane-pair split (R17/R29), scan LDS elimination (R18), serial proj fusion
// (R20), NCH=512 (R22/R25), span-major k_fix lanes (R23), independent-exp2 ar (R27).
//
// v_t = beta*v + alpha*inp ; h_t = a_t*h + v ; a_t = exp(dt*A_n)
// chunk map: h_end = Pa*H0 + cv*V0 + hhat ; v_end = beta^LCH*V0 + vhat
// map compose C=B∘A: P=BP*AP; q=BP*Aq+Bq*Aw; h=BP*Ah+Bq*Av+Bh; v=Bw*Av+Bv; w=Bw*Aw

#define D_IN 512
#define D_ST 16
#define DTR  32
#define BSZ  2
#define LSEQ 4096
#define PDIM 64
#define NCH  256
#define LCH  (LSEQ / NCH)  // 16
#define LOG2E 1.44269504f
#define LN2   0.69314718f

typedef __attribute__((ext_vector_type(8))) short short8;
typedef __attribute__((ext_vector_type(4))) float f32x4;
typedef _Float16 f16;
typedef __attribute__((ext_vector_type(8))) _Float16 f16x8;

__device__ inline float fast_exp2(float x) { return __builtin_amdgcn_exp2f(x); }
__device__ inline float fast_log2(float x) { return __builtin_amdgcn_logf(x); }

__device__ inline unsigned short bf16_rne(float f) {
  unsigned b = __float_as_uint(f);
  return (unsigned short)((b + 0x7fffu + ((b >> 16) & 1u)) >> 16);
}

__device__ inline void cvt8(const float4 u, const float4 v, short8& hi, short8& lo) {
  float f[8] = {u.x, u.y, u.z, u.w, v.x, v.y, v.z, v.w};
#pragma unroll
  for (int i = 0; i < 8; ++i) {
    unsigned short h = bf16_rne(f[i]);
    hi[i] = (short)h;
    float r = f[i] - __uint_as_float((unsigned)h << 16);
    lo[i] = (short)bf16_rne(r);
  }
}

__device__ inline void st16h(f16* p, const float* s) {
  f16 t[16];
#pragma unroll
  for (int i = 0; i < 16; ++i) t[i] = (f16)s[i];
  *(f16x8*)p = *(f16x8*)&t[0];
  *(f16x8*)(p + 8) = *(f16x8*)&t[8];
}
__device__ inline void ld16h(const f16* p, float* d) {
  f16x8 a = *(const f16x8*)p;
  f16x8 b = *(const f16x8*)(p + 8);
#pragma unroll
  for (int i = 0; i < 8; ++i) { d[i] = (float)a[i]; d[8 + i] = (float)b[i]; }
}

// pw check: A2[n] = -exp(A_log[d][n])*LOG2E is an arithmetic progression
#define PWCHK(val, n)                                                        \
  pw = pw && (fabsf((val) - (float)((n) + 1) * a0) <=                        \
              2e-5f * fabsf((float)((n) + 1) * a0));

__device__ inline bool detectA2(const float* __restrict__ A_log, int d, float& a0) {
  const float4* ap = (const float4*)(A_log + (size_t)d * D_ST);
  float4 r0 = ap[0], r1 = ap[1], r2 = ap[2], r3 = ap[3];
  float4 e0 = make_float4(-__expf(r0.x) * LOG2E, -__expf(r0.y) * LOG2E,
                          -__expf(r0.z) * LOG2E, -__expf(r0.w) * LOG2E);
  float4 e1 = make_float4(-__expf(r1.x) * LOG2E, -__expf(r1.y) * LOG2E,
                          -__expf(r1.z) * LOG2E, -__expf(r1.w) * LOG2E);
  float4 e2 = make_float4(-__expf(r2.x) * LOG2E, -__expf(r2.y) * LOG2E,
                          -__expf(r2.z) * LOG2E, -__expf(r2.w) * LOG2E);
  float4 e3 = make_float4(-__expf(r3.x) * LOG2E, -__expf(r3.y) * LOG2E,
                          -__expf(r3.z) * LOG2E, -__expf(r3.w) * LOG2E);
  a0 = e0.x;
  bool pw = true;
  PWCHK(e0.y, 1) PWCHK(e0.z, 2) PWCHK(e0.w, 3)
  PWCHK(e1.x, 4) PWCHK(e1.y, 5) PWCHK(e1.z, 6) PWCHK(e1.w, 7)
  PWCHK(e2.x, 8) PWCHK(e2.y, 9) PWCHK(e2.z, 10) PWCHK(e2.w, 11)
  PWCHK(e3.x, 12) PWCHK(e3.y, 13) PWCHK(e3.z, 14) PWCHK(e3.w, 15)
  return pw;
}

// ---------------- proj = x @ W^T via MFMA bf16x3, 4-wave K-split -------------
// W is loaded f32 and hi/lo-split in-register (== old k_wprep output, bitwise).
#define MM3(ACC, AH, AL, BH, BL)                                        \
  ACC = __builtin_amdgcn_mfma_f32_16x16x32_bf16(AL, BH, ACC, 0, 0, 0);  \
  ACC = __builtin_amdgcn_mfma_f32_16x16x32_bf16(AH, BL, ACC, 0, 0, 0);  \
  ACC = __builtin_amdgcn_mfma_f32_16x16x32_bf16(AH, BH, ACC, 0, 0, 0);

#define LOADBF(P, S)                                          \
  {                                                           \
    const int kb = (S) * 32;                                  \
    float4 a0 = *(const float4*)(wr + kb);                    \
    float4 b0 = *(const float4*)(wr + kb + 4);                \
    float4 a1 = *(const float4*)(wr + 8192 + kb);             \
    float4 b1 = *(const float4*)(wr + 8192 + kb + 4);         \
    float4 a2 = *(const float4*)(wr + 16384 + kb);            \
    float4 b2 = *(const float4*)(wr + 16384 + kb + 4);        \
    float4 a3 = *(const float4*)(wr + 24576 + kb);            \
    float4 b3 = *(const float4*)(wr + 24576 + kb + 4);        \
    cvt8(a0, b0, P##h0, P##l0);                               \
    cvt8(a1, b1, P##h1, P##l1);                               \
    cvt8(a2, b2, P##h2, P##l2);                               \
    cvt8(a3, b3, P##h3, P##l3);                               \
  }

#define LOADA(Aa, Ab, S)                              \
  {                                                   \
    const int ka = (S) * 32;                          \
    Aa = *(const float4*)(xr + ka);                   \
    Ab = *(const float4*)(xr + ka + 4);               \
  }

#define COMPSTEP(Aa, Ab, P)                           \
  {                                                   \
    short8 ahi, alo;                                  \
    cvt8(Aa, Ab, ahi, alo);                           \
    MM3(acc0, ahi, alo, P##h0, P##l0);                \
    MM3(acc1, ahi, alo, P##h1, P##l1);                \
    MM3(acc2, ahi, alo, P##h2, P##l2);                \
    MM3(acc3, ahi, alo, P##h3, P##l3);                \
  }

__global__ __launch_bounds__(256) void k_proj(const float* __restrict__ x,
                                              const float* __restrict__ W,
                                              float* __restrict__ proj) {
  __shared__ float Pacc[4][16][64];  // 16 KB: per-wave partial C tiles
  const int row0 = blockIdx.x * 16;
  const int l = threadIdx.x & 63;
  const int wq = threadIdx.x >> 6;             // K-quarter owner
  const int m = l & 15;
  const int ko = (l >> 4) * 8 + wq * 128;      // this wave's K window
  const float* xr = x + (size_t)(row0 + m) * D_IN + ko;
  const float* wr = W + (size_t)m * D_IN + ko;

  f32x4 acc0 = {0.f, 0.f, 0.f, 0.f}, acc1 = acc0, acc2 = acc0, acc3 = acc0;
  float4 A0a, A0b, A1a, A1b, A2a, A2b, A3a, A3b;
  short8 Xh0, Xh1, Xh2, Xh3, Xl0, Xl1, Xl2, Xl3;
  short8 Yh0, Yh1, Yh2, Yh3, Yl0, Yl1, Yl2, Yl3;
  LOADA(A0a, A0b, 0); LOADA(A1a, A1b, 1); LOADA(A2a, A2b, 2); LOADA(A3a, A3b, 3);
  LOADBF(X, 0); LOADBF(Y, 1);

  COMPSTEP(A0a, A0b, X); LOADBF(X, 2);
  COMPSTEP(A1a, A1b, Y); LOADBF(Y, 3);
  COMPSTEP(A2a, A2b, X);
  COMPSTEP(A3a, A3b, Y);

  const int r0 = (l >> 4) * 4;
#pragma unroll
  for (int r = 0; r < 4; ++r) {
    Pacc[wq][r0 + r][m] = acc0[r];
    Pacc[wq][r0 + r][16 + m] = acc1[r];
    Pacc[wq][r0 + r][32 + m] = acc2[r];
    Pacc[wq][r0 + r][48 + m] = acc3[r];
  }
  __syncthreads();

  const int orow = threadIdx.x >> 4;           // 0..15
  const int ocol = (threadIdx.x & 15) * 4;     // 0..60
  float4 s0 = *(const float4*)&Pacc[0][orow][ocol];
  float4 s1 = *(const float4*)&Pacc[1][orow][ocol];
  float4 s2 = *(const float4*)&Pacc[2][orow][ocol];
  float4 s3 = *(const float4*)&Pacc[3][orow][ocol];
  float4 o = make_float4((s0.x + s1.x) + (s2.x + s3.x), (s0.y + s1.y) + (s2.y + s3.y),
                         (s0.z + s1.z) + (s2.z + s3.z), (s0.w + s1.w) + (s2.w + s3.w));
  *(float4*)(proj + (size_t)(row0 + orow) * PDIM + ocol) = o;
}

// ---------------- pass 1: LDS-free, dt inline, zero-init scan ----------------
#define S1_LOOP                                                              \
  _Pragma("unroll")                                                          \
  for (int j = 0; j < LCH; ++j) {                                            \
    const float4* pj = (const float4*)(pb + j * PDIM);                       \
    float4 pp[8];                                                            \
    _Pragma("unroll")                                                        \
    for (int k = 0; k < 8; ++k) pp[k] = pj[k];                               \
    float c0 = bb, c1 = 0.f, c2 = 0.f, c3 = 0.f;                             \
    _Pragma("unroll")                                                        \
    for (int k = 0; k < 8; ++k) {                                            \
      c0 = fmaf(pp[k].x, w4[k].x, c0);                                       \
      c1 = fmaf(pp[k].y, w4[k].y, c1);                                       \
      c2 = fmaf(pp[k].z, w4[k].z, c2);                                       \
      c3 = fmaf(pp[k].w, w4[k].w, c3);                                       \
    }                                                                        \
    const float acc = (c0 + c1) + (c2 + c3);                                 \
    const float ee = fast_exp2(acc * LOG2E);                                 \
    const float dtc = (acc > 20.f) ? acc : LN2 * fast_log2(1.f + ee);        \
    dp[(size_t)j * D_IN] = (f16)dtc;                                         \
    sd += dtc;                                                               \
    bpow *= beta;                                                            \
    const float u = alpha * dtc * xs[j];                                     \
    float4 bq[4];                                                            \
    _Pragma("unroll")                                                        \
    for (int k = 0; k < 4; ++k) bq[k] = pj[8 + k];                           \
    const float* Bf = (const float*)bq;                                      \
    AR_INIT;                                                                 \
    _Pragma("unroll")                                                        \
    for (int n = 0; n < 16; ++n) {                                           \
      AR_STEP;                                                               \
      v[n] = fmaf(beta, v[n], u * Bf[n]);                                    \
      h[n] = fmaf(ar, h[n], v[n]);                                           \
      cv[n] = fmaf(ar, cv[n], bpow);                                         \
    }                                                                        \
  }

__global__ __launch_bounds__(256) void k_scan1(const float* __restrict__ x,
                                               const float* __restrict__ proj,
                                               const float* __restrict__ A_log,
                                               const float* __restrict__ W_dt,
                                               const float* __restrict__ b_dt,
                                               const float* __restrict__ alpha_p,
                                               const float* __restrict__ beta_p,
                                               f16* __restrict__ hh,
                                               f16* __restrict__ vh,
                                               f16* __restrict__ cvv,
                                               float* __restrict__ sdt,
                                               f16* __restrict__ dth) {
  const int c = blockIdx.x, b = blockIdx.z;
  const int d = blockIdx.y * 256 + threadIdx.x;
  const int t0 = c * LCH;
  const float* pb = proj + ((size_t)b * LSEQ + t0) * PDIM;  // uniform addr

  float xs[LCH];
  {
    const float* xp = x + ((size_t)b * LSEQ + t0) * D_IN + d;
#pragma unroll
    for (int j = 0; j < LCH; ++j) xs[j] = xp[(size_t)j * D_IN];
  }
  float4 w4[8];
  {
    const float4* wp = (const float4*)(W_dt + (size_t)d * DTR);
#pragma unroll
    for (int i = 0; i < 8; ++i) w4[i] = wp[i];
  }
  const float bb = b_dt[d];
  const float alpha = alpha_p[0];
  const float beta = 1.f / (1.f + __expf(-beta_p[0]));
  float a0;
  const bool pw = detectA2(A_log, d, a0);

  f16* dp = dth + ((size_t)b * LSEQ + t0) * D_IN + d;
  float h[16] = {}, v[16] = {}, cv[16] = {};
  float bpow = 1.f, sd = 0.f;

  if (pw) {
#define AR_INIT const float r = fast_exp2(dtc * a0); float ar = 1.f
#define AR_STEP ar *= r
    S1_LOOP
#undef AR_INIT
#undef AR_STEP
  } else {
    volatile const float* av = A_log + (size_t)d * D_ST;
#define AR_INIT float ar
#define AR_STEP ar = fast_exp2(dtc * (-__expf(av[n]) * LOG2E))
    S1_LOOP
#undef AR_INIT
#undef AR_STEP
  }

  const size_t base = ((size_t)(b * NCH + c) * D_IN + d) * D_ST;
  st16h(hh + base, h);
  st16h(vh + base, v);
  st16h(cvv + base, cv);
  sdt[(size_t)(b * NCH + c) * D_IN + d] = sd;
}

// ---------------- fixup: parallel affine scan, coalesced ---------------------
// Block = 1024 threads = 16 waves; covers 64 consecutive series (lane = dn off).
// Wave w owns chunks [16w, 16w+16). Fold in regs (coalesced 128B loads, data
// retained), maps via LDS, serial exclusive compose over preceding spans,
// apply + write from regs. NOTE: 1024-thr blocks cap VGPR at 64 (R25) — the
// 64-float retention here is at the edge; do NOT enlarge CPS.
__global__ __launch_bounds__(1024) void k_fix(f16* __restrict__ hh,
                                              f16* __restrict__ vh,
                                              const f16* __restrict__ cvv,
                                              const float* __restrict__ sdt,
                                              const float* __restrict__ A_log,
                                              const float* __restrict__ beta_p) {
  __shared__ float M[16][5][64];  // 20 KB span maps
  const int lane = threadIdx.x & 63;
  const int w = threadIdx.x >> 6;         // span 0..15
  const int g = blockIdx.x * 64 + lane;   // series id
  const int b = g >> 13;
  const int dn = g & 8191;
  const float beta = 1.f / (1.f + __expf(-beta_p[0]));
  const float A2 = -__expf(A_log[dn]) * LOG2E;
  float bL = beta;
#pragma unroll
  for (int i = 0; i < 4; ++i) bL *= bL;  // beta^16 = beta^LCH

  const size_t cs = (size_t)D_IN * D_ST;
  const size_t base = (size_t)b * NCH * cs + dn;
  const size_t sbase = (size_t)b * NCH * D_IN + (dn >> 4);
  const int c0 = w * 16;

  // fold 16 chunks (coalesced; keep data for apply phase)
  float hc[16], vc[16], cvc[16], Pa[16];
#pragma unroll
  for (int i = 0; i < 16; ++i) {
    const int c = c0 + i;
    hc[i] = (float)hh[base + (size_t)c * cs];
    vc[i] = (float)vh[base + (size_t)c * cs];
    cvc[i] = (float)cvv[base + (size_t)c * cs];
    Pa[i] = fast_exp2(sdt[sbase + (size_t)c * D_IN] * A2);
  }
  float SP = 1.f, Sq = 0.f, Sh = 0.f, Sv = 0.f, Sw = 1.f;
#pragma unroll
  for (int i = 0; i < 16; ++i) {
    Sq = fmaf(Pa[i], Sq, cvc[i] * Sw);
    Sh = fmaf(Pa[i], Sh, fmaf(cvc[i], Sv, hc[i]));
    SP = Pa[i] * SP;
    Sv = fmaf(bL, Sv, vc[i]);
    Sw = bL * Sw;
  }
  M[w][0][lane] = SP; M[w][1][lane] = Sq; M[w][2][lane] = Sh;
  M[w][3][lane] = Sv; M[w][4][lane] = Sw;
  __syncthreads();

  // exclusive carry-in: iterate preceding spans in chunk order (== serial order)
  float H = 0.f, V = 0.f;
  for (int s = 0; s < w; ++s) {  // wave-uniform bound; lane-consecutive LDS reads
    const float P = M[s][0][lane], q = M[s][1][lane], h = M[s][2][lane];
    const float vv = M[s][3][lane], ww = M[s][4][lane];
    const float Hn = fmaf(P, H, fmaf(q, V, h));
    V = fmaf(ww, V, vv);
    H = Hn;
  }

  // apply + write (coalesced)
#pragma unroll
  for (int i = 0; i < 16; ++i) {
    const int c = c0 + i;
    hh[base + (size_t)c * cs] = (f16)H;
    vh[base + (size_t)c * cs] = (f16)V;
    const float Hn = fmaf(Pa[i], H, fmaf(cvc[i], V, hc[i]));
    V = fmaf(bL, V, vc[i]);
    H = Hn;
  }
}

// ---------------- pass 2: LDS-free, read dt(fp16)+x, emit y ------------------
#define S2_LOOP                                                              \
  _Pragma("unroll")                                                          \
  for (int j = 0; j < LCH; ++j) {                                            \
    const float4* pj = (const float4*)(pb + j * PDIM);                       \
    float4 bq[8];                                                            \
    _Pragma("unroll")                                                        \
    for (int k = 0; k < 8; ++k) bq[k] = pj[8 + k];                           \
    const float* Bf = (const float*)bq;                                      \
    const float dtc = dtv[j], xv = xs[j];                                    \
    const float u = alpha * dtc * xv;                                        \
    float y0 = 0.f, y1 = 0.f, y2 = 0.f, y3 = 0.f;                            \
    AR_INIT;                                                                 \
    _Pragma("unroll")                                                        \
    for (int n = 0; n < 16; ++n) {                                           \
      AR_STEP;                                                               \
      v[n] = fmaf(beta, v[n], u * Bf[n]);                                    \
      h[n] = fmaf(ar, h[n], v[n]);                                           \
      float hc = h[n] * Bf[16 + n];                                          \
      if ((n & 3) == 0) y0 += hc;                                            \
      else if ((n & 3) == 1) y1 += hc;                                       \
      else if ((n & 3) == 2) y2 += hc;                                       \
      else y3 += hc;                                                         \
    }                                                                        \
    op[(size_t)j * D_IN] = (y0 + y1) + (y2 + y3) + Dv * xv;                  \
  }

__global__ __launch_bounds__(256) void k_scan2(const float* __restrict__ x,
                                               const f16* __restrict__ dth,
                                               const float* __restrict__ proj,
                                               const float* __restrict__ A_log,
                                               const float* __restrict__ D_param,
                                               const float* __restrict__ alpha_p,
                                               const float* __restrict__ beta_p,
                                               const f16* __restrict__ hh,
                                               const f16* __restrict__ vh,
                                               float* __restrict__ out) {
  const int c = blockIdx.x, b = blockIdx.z;
  const int d = blockIdx.y * 256 + threadIdx.x;
  const int t0 = c * LCH;
  const float* pb = proj + ((size_t)b * LSEQ + t0) * PDIM;  // uniform addr

  float xs[LCH], dtv[LCH];
  {
    const float* xp = x + ((size_t)b * LSEQ + t0) * D_IN + d;
    const f16* dp = dth + ((size_t)b * LSEQ + t0) * D_IN + d;
#pragma unroll
    for (int j = 0; j < LCH; ++j) xs[j] = xp[(size_t)j * D_IN];
#pragma unroll
    for (int j = 0; j < LCH; ++j) dtv[j] = (float)dp[(size_t)j * D_IN];
  }
  const float alpha = alpha_p[0];
  const float beta = 1.f / (1.f + __expf(-beta_p[0]));
  const float Dv = D_param[d];
  float a0;
  const bool pw = detectA2(A_log, d, a0);
  const size_t ibase = ((size_t)(b * NCH + c) * D_IN + d) * D_ST;
  float h[16], v[16];
  ld16h(hh + ibase, h);
  ld16h(vh + ibase, v);

  float* op = out + ((size_t)b * LSEQ + t0) * D_IN + d;
  if (pw) {
#define AR_INIT const float r = fast_exp2(dtc * a0); float ar = 1.f
#define AR_STEP ar *= r
    S2_LOOP
#undef AR_INIT
#undef AR_STEP
  } else {
    volatile const float* av = A_log + (size_t)d * D_ST;
#define AR_INIT float ar
#define AR_STEP ar = fast_exp2(dtc * (-__expf(av[n]) * LOG2E))
    S2_LOOP
#undef AR_INIT
#undef AR_STEP
  }
}

extern "C" void kernel_launch(void* const* d_in, const int* in_sizes, int n_in,
                              void* d_out, int out_size, void* d_ws, size_t ws_size,
                              hipStream_t stream) {
  const float* x = (const float*)d_in[0];
  const float* A_log = (const float*)d_in[1];
  const float* D_param = (const float*)d_in[2];
  const float* W_xproj = (const float*)d_in[3];
  const float* W_dt = (const float*)d_in[4];
  const float* b_dt = (const float*)d_in[5];
  const float* alpha = (const float*)d_in[6];
  const float* beta_logit = (const float*)d_in[7];
  float* out = (float*)d_out;

  const size_t NST = (size_t)BSZ * NCH * D_IN * D_ST;  // 4194304
  float* ws = (float*)d_ws;
  float* proj = ws;                                  // 524288 floats
  float* sdt = proj + (size_t)BSZ * LSEQ * PDIM;     // 262144 floats
  f16* hh = (f16*)(sdt + (size_t)BSZ * NCH * D_IN);  // 4194304 halves
  f16* vh = hh + NST;
  f16* cvv = vh + NST;
  f16* dth = cvv + NST;                              // B*L*D halves; total ~35 MB

  k_proj<<<dim3(BSZ * LSEQ / 16), dim3(256), 0, stream>>>(x, W_xproj, proj);
  k_scan1<<<dim3(NCH, D_IN / 256, BSZ), dim3(256), 0, stream>>>(
      x, proj, A_log, W_dt, b_dt, alpha, beta_logit, hh, vh, cvv, sdt, dth);
  k_fix<<<dim3(BSZ * D_IN * D_ST / 64), dim3(1024), 0, stream>>>(hh, vh, cvv, sdt,
                                                                 A_log, beta_logit);
  k_scan2<<<dim3(NCH, D_IN / 256, BSZ), dim3(256), 0, stream>>>(
      x, dth, proj, A_log, D_param, alpha, beta_logit, hh, vh, out);
}